// Round 7
// baseline (210.138 us; speedup 1.0000x reference)
//
#include <hip/hip_runtime.h>

#define DIM 64

// ---- parallel counting-sort pipeline: zero(memset) -> hist -> scan -> scatter

__global__ __launch_bounds__(256) void k_hist(const int* __restrict__ m2,
                                              int* __restrict__ cnt, int N) {
    const int i = blockIdx.x * 256 + threadIdx.x;
    if (i < N) atomicAdd(&cnt[m2[i] >> 7], 1);
}

__global__ __launch_bounds__(256) void k_scan(int* __restrict__ cnt, int nbuck) {
    __shared__ int s[256];
    const int tid  = threadIdx.x;
    const int base = tid * 10;
    int loc[10];
    int sum = 0;
    #pragma unroll
    for (int u = 0; u < 10; ++u) {
        const int idx = base + u;
        const int v = (idx < nbuck) ? cnt[idx] : 0;
        loc[u] = sum;
        sum += v;
    }
    s[tid] = sum;
    __syncthreads();
    for (int off = 1; off < 256; off <<= 1) {
        const int v = (tid >= off) ? s[tid - off] : 0;
        __syncthreads();
        s[tid] += v;
        __syncthreads();
    }
    const int excl = (tid > 0) ? s[tid - 1] : 0;
    #pragma unroll
    for (int u = 0; u < 10; ++u) {
        const int idx = base + u;
        if (idx < nbuck) cnt[idx] = excl + loc[u];
    }
}

__global__ __launch_bounds__(256) void k_scatter(const int* __restrict__ m1,
                                                 const int* __restrict__ m2,
                                                 int* __restrict__ cnt,
                                                 int* __restrict__ i1s,
                                                 int* __restrict__ i2s, int N) {
    const int i = blockIdx.x * 256 + threadIdx.x;
    if (i < N) {
        const int v2  = m2[i];
        const int pos = atomicAdd(&cnt[v2 >> 7], 1);
        i1s[pos] = m1[i];
        i2s[pos] = v2;
    }
}

// ---- main: one block (320 thr = 5 waves) per sorted match.
//      80 groups x 4 lanes; one score per group (group 64 also does j=80).
//      One barrier; epilogue entirely in wave 0 registers. ----
__global__ __launch_bounds__(320) void pixel_ap_main(
    const float* __restrict__ d1, const float* __restrict__ d2,
    const float* __restrict__ qw, const float* __restrict__ qb,
    const int* __restrict__ offs,
    const int* __restrict__ i1s, const int* __restrict__ i2s,
    float* __restrict__ partial, int P, int NEG, int NQ2, int N)
{
    const int tid = threadIdx.x;
    const int nq  = NQ2 >> 1;
    const int M   = NEG + 1;          // 81 scores

    __shared__ float s_scores[96];

    // XCD-aware contiguous slice of sorted order (block b -> XCD b%8)
    const int b   = blockIdx.x;
    const int per = gridDim.x >> 3;                 // gridDim = 8*per
    const int pos = (b & 7) * per + (b >> 3);       // bijection onto [0, 8*per)
    if (pos >= N) return;

    const int i1 = i1s[pos];
    const int i2 = i2s[pos];

    const int g  = tid >> 2;          // group 0..79: score j = g
    const int sl = tid & 3;           // 4 lanes; each loads 4 interleaved float4

    // a fragment: float4 indices sl, sl+4, sl+8, sl+12 of d1 row i1
    const float4* a_row = (const float4*)(d1 + (size_t)i1 * DIM);
    const float4 a0 = a_row[sl];
    const float4 a1 = a_row[sl + 4];
    const float4 a2 = a_row[sl + 8];
    const float4 a3 = a_row[sl + 12];

    // score j = g
    {
        const int row = (g == 0) ? i2 : min(i2 + offs[g - 1], P - 1);
        const float4* p = (const float4*)(d2 + (size_t)row * DIM);
        const float4 b0 = p[sl];
        const float4 b1 = p[sl + 4];
        const float4 b2 = p[sl + 8];
        const float4 b3 = p[sl + 12];
        float s = b0.x * a0.x + b0.y * a0.y + b0.z * a0.z + b0.w * a0.w
                + b1.x * a1.x + b1.y * a1.y + b1.z * a1.z + b1.w * a1.w
                + b2.x * a2.x + b2.y * a2.y + b2.z * a2.z + b2.w * a2.w
                + b3.x * a3.x + b3.y * a3.y + b3.z * a3.z + b3.w * a3.w;
        s += __shfl_xor(s, 1);
        s += __shfl_xor(s, 2);
        if (sl == 0) s_scores[g] = s;
    }
    // score j = 80 handled by group 64 (wave 4, keeps wave 0 light)
    if (g == 64) {
        const int row = min(i2 + offs[79], P - 1);
        const float4* p = (const float4*)(d2 + (size_t)row * DIM);
        const float4 b0 = p[sl];
        const float4 b1 = p[sl + 4];
        const float4 b2 = p[sl + 8];
        const float4 b3 = p[sl + 12];
        float s = b0.x * a0.x + b0.y * a0.y + b0.z * a0.z + b0.w * a0.w
                + b1.x * a1.x + b1.y * a1.y + b1.z * a1.z + b1.w * a1.w
                + b2.x * a2.x + b2.y * a2.y + b2.z * a2.z + b2.w * a2.w
                + b3.x * a3.x + b3.y * a3.y + b3.z * a3.z + b3.w * a3.w;
        s += __shfl_xor(s, 1);
        s += __shfl_xor(s, 2);
        if (sl == 0) s_scores[80] = s;
    }
    __syncthreads();
    if (tid >= 64) return;            // waves 1..4 retire; wave 0 does epilogue

    // ---- hat-basis AP epilogue, single wave, in-register ----
    const float a_scale = qw[nq];               // +a
    const float amn     = qb[nq - 1] - 1.0f;    // a*mn
    const float ulim    = (float)(nq - 1);

    const float xp = s_scores[0];
    const float up = fminf(fmaxf(a_scale * xp - amn, 0.0f), ulim);
    const float ip = floorf(up);
    const float fp = up - ip;

    float n1 = 0.0f, n2 = 0.0f;
    {
        const float x  = s_scores[tid];
        const float u  = fminf(fmaxf(a_scale * x - amn, 0.0f), ulim);
        const float fi = floorf(u);
        const float f  = u - fi;
        n2 += (fi >= ip)        ? 1.0f : ((fi == ip - 1.0f) ? f : 0.0f);
        n1 += (fi >= ip + 1.0f) ? 1.0f : ((fi == ip)        ? f : 0.0f);
    }
    if (tid + 64 < M) {
        const float x  = s_scores[tid + 64];
        const float u  = fminf(fmaxf(a_scale * x - amn, 0.0f), ulim);
        const float fi = floorf(u);
        const float f  = u - fi;
        n2 += (fi >= ip)        ? 1.0f : ((fi == ip - 1.0f) ? f : 0.0f);
        n1 += (fi >= ip + 1.0f) ? 1.0f : ((fi == ip)        ? f : 0.0f);
    }
    #pragma unroll
    for (int off = 32; off >= 1; off >>= 1) {
        n1 += __shfl_xor(n1, off);
        n2 += __shfl_xor(n2, off);
    }
    if (tid == 0) {
        const float ap = fp * fp / (1e-16f + n1) + (1.0f - fp) / (1e-16f + n2);
        partial[pos] = 1.0f - ap;
    }
}

// ---- single-block final reduction ----
__global__ __launch_bounds__(1024) void k_reduce(const float* __restrict__ partial,
                                                 float* __restrict__ out, int N)
{
    float s = 0.0f;
    for (int i = threadIdx.x; i < N; i += 1024) s += partial[i];
    #pragma unroll
    for (int off = 32; off >= 1; off >>= 1) s += __shfl_xor(s, off);
    __shared__ float sw[16];
    if ((threadIdx.x & 63) == 0) sw[threadIdx.x >> 6] = s;
    __syncthreads();
    if (threadIdx.x == 0) {
        float t = 0.0f;
        #pragma unroll
        for (int w = 0; w < 16; ++w) t += sw[w];
        out[0] = t / (float)N;
    }
}

extern "C" void kernel_launch(void* const* d_in, const int* in_sizes, int n_in,
                              void* d_out, int out_size, void* d_ws, size_t ws_size,
                              hipStream_t stream) {
    const float* d1   = (const float*)d_in[0];
    const float* d2   = (const float*)d_in[1];
    const float* qw   = (const float*)d_in[2];
    const float* qb   = (const float*)d_in[3];
    const int*   m1   = (const int*)d_in[4];
    const int*   m2   = (const int*)d_in[5];
    const int*   offs = (const int*)d_in[6];

    const int N     = in_sizes[4];
    const int P     = in_sizes[0] / DIM;
    const int NEG   = in_sizes[6];
    const int NQ2   = in_sizes[2];
    const int nbuck = (P + 127) >> 7;

    int*   cnt     = (int*)d_ws;
    int*   i1s     = cnt + nbuck;
    int*   i2s     = i1s + N;
    float* partial = (float*)(i2s + N);

    const int nblk = (N + 255) / 256;

    hipMemsetAsync(cnt, 0, (size_t)nbuck * sizeof(int), stream);
    k_hist   <<<nblk, 256, 0, stream>>>(m2, cnt, N);
    k_scan   <<<1, 256, 0, stream>>>(cnt, nbuck);
    k_scatter<<<nblk, 256, 0, stream>>>(m1, m2, cnt, i1s, i2s, N);

    const int per = (N + 7) / 8;
    pixel_ap_main<<<8 * per, 320, 0, stream>>>(d1, d2, qw, qb, offs, i1s, i2s,
                                               partial, P, NEG, NQ2, N);

    k_reduce<<<1, 1024, 0, stream>>>(partial, (float*)d_out, N);
}

// Round 8
// 199.856 us; speedup vs baseline: 1.0514x; 1.0514x over previous
//
#include <hip/hip_runtime.h>

#define DIM 64

// ---- parallel counting-sort pipeline: zero(memset) -> hist -> scan -> scatter

__global__ __launch_bounds__(256) void k_hist(const int* __restrict__ m2,
                                              int* __restrict__ cnt, int N) {
    const int i = blockIdx.x * 256 + threadIdx.x;
    if (i < N) atomicAdd(&cnt[m2[i] >> 7], 1);
}

__global__ __launch_bounds__(256) void k_scan(int* __restrict__ cnt, int nbuck) {
    __shared__ int s[256];
    const int tid  = threadIdx.x;
    const int base = tid * 10;
    int loc[10];
    int sum = 0;
    #pragma unroll
    for (int u = 0; u < 10; ++u) {
        const int idx = base + u;
        const int v = (idx < nbuck) ? cnt[idx] : 0;
        loc[u] = sum;
        sum += v;
    }
    s[tid] = sum;
    __syncthreads();
    for (int off = 1; off < 256; off <<= 1) {
        const int v = (tid >= off) ? s[tid - off] : 0;
        __syncthreads();
        s[tid] += v;
        __syncthreads();
    }
    const int excl = (tid > 0) ? s[tid - 1] : 0;
    #pragma unroll
    for (int u = 0; u < 10; ++u) {
        const int idx = base + u;
        if (idx < nbuck) cnt[idx] = excl + loc[u];
    }
}

__global__ __launch_bounds__(256) void k_scatter(const int* __restrict__ m1,
                                                 const int* __restrict__ m2,
                                                 int* __restrict__ cnt,
                                                 int* __restrict__ i1s,
                                                 int* __restrict__ i2s, int N) {
    const int i = blockIdx.x * 256 + threadIdx.x;
    if (i < N) {
        const int v2  = m2[i];
        const int pos = atomicAdd(&cnt[v2 >> 7], 1);
        i1s[pos] = m1[i];
        i2s[pos] = v2;
    }
}

// ---- main: one block (256 thr) per TWO adjacent sorted matches.
//      R6's proven 32-group x 8-lane shape; 12 b-loads in flight per lane;
//      one barrier; epilogues on waves 0 (match A) and 1 (match B). ----
__global__ __launch_bounds__(256) void pixel_ap_main(
    const float* __restrict__ d1, const float* __restrict__ d2,
    const float* __restrict__ qw, const float* __restrict__ qb,
    const int* __restrict__ offs,
    const int* __restrict__ i1s, const int* __restrict__ i2s,
    float* __restrict__ partial, int P, int NEG, int NQ2, int N)
{
    const int tid = threadIdx.x;
    const int nq  = NQ2 >> 1;
    const int M   = NEG + 1;          // 81 scores per match

    __shared__ float s_scores[2][96];

    // XCD-aware contiguous slice over pair-index space (block b -> XCD b%8)
    const int b    = blockIdx.x;
    const int per  = gridDim.x >> 3;                // gridDim = 8*per
    const int pr   = (b & 7) * per + (b >> 3);      // pair index
    const int posA = 2 * pr;
    const int posB = posA + 1;
    if (posA >= N) return;
    const bool hasB = (posB < N);

    const int i1A = i1s[posA];
    const int i2A = i2s[posA];
    const int i1B = hasB ? i1s[posB] : i1A;
    const int i2B = hasB ? i2s[posB] : i2A;

    const int g  = tid >> 3;          // group 0..31
    const int sl = tid & 7;           // 8 lanes x 32 B = 256 B per row

    // a fragments for both matches
    const float* aA = d1 + (size_t)i1A * DIM + 8 * sl;
    const float* aB = d1 + (size_t)i1B * DIM + 8 * sl;
    const float4 a0A = ((const float4*)aA)[0];
    const float4 a1A = ((const float4*)aA)[1];
    const float4 a0B = ((const float4*)aB)[0];
    const float4 a1B = ((const float4*)aB)[1];

    // row indices for 3 scores per match
    int rA[3], rB[3];
    #pragma unroll
    for (int t = 0; t < 3; ++t) {
        const int j = g + 32 * t;
        if (j < M) {
            const int o = (j == 0) ? 0 : offs[j - 1];
            rA[t] = (j == 0) ? i2A : min(i2A + o, P - 1);
            rB[t] = (j == 0) ? i2B : min(i2B + o, P - 1);
        }
    }

    // all 12 loads issued before any math
    float4 b0A[3], b1A[3], b0B[3], b1B[3];
    #pragma unroll
    for (int t = 0; t < 3; ++t) {
        const int j = g + 32 * t;
        if (j < M) {
            const float* pA = d2 + (size_t)rA[t] * DIM + 8 * sl;
            b0A[t] = ((const float4*)pA)[0];
            b1A[t] = ((const float4*)pA)[1];
            const float* pB = d2 + (size_t)rB[t] * DIM + 8 * sl;
            b0B[t] = ((const float4*)pB)[0];
            b1B[t] = ((const float4*)pB)[1];
        }
    }
    #pragma unroll
    for (int t = 0; t < 3; ++t) {
        const int j = g + 32 * t;
        if (j < M) {
            float sA = b0A[t].x * a0A.x + b0A[t].y * a0A.y + b0A[t].z * a0A.z + b0A[t].w * a0A.w
                     + b1A[t].x * a1A.x + b1A[t].y * a1A.y + b1A[t].z * a1A.z + b1A[t].w * a1A.w;
            float sB = b0B[t].x * a0B.x + b0B[t].y * a0B.y + b0B[t].z * a0B.z + b0B[t].w * a0B.w
                     + b1B[t].x * a1B.x + b1B[t].y * a1B.y + b1B[t].z * a1B.z + b1B[t].w * a1B.w;
            sA += __shfl_xor(sA, 1);
            sA += __shfl_xor(sA, 2);
            sA += __shfl_xor(sA, 4);
            sB += __shfl_xor(sB, 1);
            sB += __shfl_xor(sB, 2);
            sB += __shfl_xor(sB, 4);
            if (sl == 0) {
                s_scores[0][j] = sA;
                s_scores[1][j] = sB;
            }
        }
    }
    __syncthreads();
    const int w = tid >> 6;           // wave id
    if (w >= 2) return;               // waves 2,3 retire
    if (w == 1 && !hasB) return;
    const int lane = tid & 63;

    // ---- hat-basis AP epilogue, one wave per match ----
    const float a_scale = qw[nq];               // +a
    const float amn     = qb[nq - 1] - 1.0f;    // a*mn
    const float ulim    = (float)(nq - 1);

    const float xp = s_scores[w][0];
    const float up = fminf(fmaxf(a_scale * xp - amn, 0.0f), ulim);
    const float ip = floorf(up);
    const float fp = up - ip;

    float n1 = 0.0f, n2 = 0.0f;
    {
        const float x  = s_scores[w][lane];
        const float u  = fminf(fmaxf(a_scale * x - amn, 0.0f), ulim);
        const float fi = floorf(u);
        const float f  = u - fi;
        n2 += (fi >= ip)        ? 1.0f : ((fi == ip - 1.0f) ? f : 0.0f);
        n1 += (fi >= ip + 1.0f) ? 1.0f : ((fi == ip)        ? f : 0.0f);
    }
    if (lane + 64 < M) {
        const float x  = s_scores[w][lane + 64];
        const float u  = fminf(fmaxf(a_scale * x - amn, 0.0f), ulim);
        const float fi = floorf(u);
        const float f  = u - fi;
        n2 += (fi >= ip)        ? 1.0f : ((fi == ip - 1.0f) ? f : 0.0f);
        n1 += (fi >= ip + 1.0f) ? 1.0f : ((fi == ip)        ? f : 0.0f);
    }
    #pragma unroll
    for (int off = 32; off >= 1; off >>= 1) {
        n1 += __shfl_xor(n1, off);
        n2 += __shfl_xor(n2, off);
    }
    if (lane == 0) {
        const float ap = fp * fp / (1e-16f + n1) + (1.0f - fp) / (1e-16f + n2);
        partial[posA + w] = 1.0f - ap;
    }
}

// ---- single-block final reduction ----
__global__ __launch_bounds__(1024) void k_reduce(const float* __restrict__ partial,
                                                 float* __restrict__ out, int N)
{
    float s = 0.0f;
    for (int i = threadIdx.x; i < N; i += 1024) s += partial[i];
    #pragma unroll
    for (int off = 32; off >= 1; off >>= 1) s += __shfl_xor(s, off);
    __shared__ float sw[16];
    if ((threadIdx.x & 63) == 0) sw[threadIdx.x >> 6] = s;
    __syncthreads();
    if (threadIdx.x == 0) {
        float t = 0.0f;
        #pragma unroll
        for (int w = 0; w < 16; ++w) t += sw[w];
        out[0] = t / (float)N;
    }
}

extern "C" void kernel_launch(void* const* d_in, const int* in_sizes, int n_in,
                              void* d_out, int out_size, void* d_ws, size_t ws_size,
                              hipStream_t stream) {
    const float* d1   = (const float*)d_in[0];
    const float* d2   = (const float*)d_in[1];
    const float* qw   = (const float*)d_in[2];
    const float* qb   = (const float*)d_in[3];
    const int*   m1   = (const int*)d_in[4];
    const int*   m2   = (const int*)d_in[5];
    const int*   offs = (const int*)d_in[6];

    const int N     = in_sizes[4];
    const int P     = in_sizes[0] / DIM;
    const int NEG   = in_sizes[6];
    const int NQ2   = in_sizes[2];
    const int nbuck = (P + 127) >> 7;

    int*   cnt     = (int*)d_ws;
    int*   i1s     = cnt + nbuck;
    int*   i2s     = i1s + N;
    float* partial = (float*)(i2s + N);

    const int nblk = (N + 255) / 256;

    hipMemsetAsync(cnt, 0, (size_t)nbuck * sizeof(int), stream);
    k_hist   <<<nblk, 256, 0, stream>>>(m2, cnt, N);
    k_scan   <<<1, 256, 0, stream>>>(cnt, nbuck);
    k_scatter<<<nblk, 256, 0, stream>>>(m1, m2, cnt, i1s, i2s, N);

    const int npair = (N + 1) / 2;
    const int per   = (npair + 7) / 8;
    pixel_ap_main<<<8 * per, 256, 0, stream>>>(d1, d2, qw, qb, offs, i1s, i2s,
                                               partial, P, NEG, NQ2, N);

    k_reduce<<<1, 1024, 0, stream>>>(partial, (float*)d_out, N);
}